// Round 5
// baseline (202.236 us; speedup 1.0000x reference)
//
#include <hip/hip_runtime.h>

// SinusoidalSynthesizer: FLOAT32 inputs [8,250,100] x2 -> FLOAT32 outputs
//   chunk0: amplitude_envelopes [8,64000,100] f32 (51,200,000) at elem 0
//   chunk1: frequency_envelopes [8,250,100]   f32 (   200,000) at elem 51,200,000
//
// R5 root cause of R1-R4 failures: inputs are f32 (setup_inputs uses
// jnp.float32; the "(bf16" in the harness error label is literal f-string
// text). Reading f32 as bf16 made even-channel values NaN ~0.4% of the time
// (mantissa u16 with exp bits all-ones); those NaNs were mantissa-hidden
// under the f32 readout in R1/R2 (bf16 stores) and exposed in R3/R4
// (f32 stores) -> the NaN@Output0 signature.
//
// Math: upsample_with_windows(hop=256, periodic hann 512) == crossfade
// (w[r] + w[256+r] == 1):
//   amp_env[b,t,c] = A[b,min(g,249),c]*w[r] + A[b,g-1,c]*(1-w[r]),
//   g = t/256 + 1, r = t%256,
//   A = (2*sigmoid(amp)^ln10 + 1e-7) * ((f*(c+1) < 22050) + 1e-4),
//   f = 440*2^((sigmoid(frq)*119.2131 - 69)/12).
// ~206 MB f32 writes -> HBM-store-bound, ~33 us floor at 6.3 TB/s.

namespace {
constexpr int kB = 8;
constexpr int kF = 250;
constexpr int kC = 100;
constexpr int kHop = 256;
constexpr int kSamples = 64000;
constexpr int kFreqElems = kB * kF * kC;                  // 200,000
constexpr size_t kAmpElems = (size_t)kB * kSamples * kC;  // 51,200,000
constexpr float kLog10 = 2.302585092994046f;
constexpr float kMidiMax = 119.213094853649121f;          // 12*(log2(8000)-log2(440))+69
constexpr float kPi = 3.14159265358979323846f;

__device__ __forceinline__ float sigmoidf_(float x) {
    return 1.0f / (1.0f + expf(-x));
}
} // namespace

__global__ __launch_bounds__(256) void amp_kernel(
    const float* amp_in,
    const float* frq_in,
    float* amp_out)
{
    const int gm1 = blockIdx.x;   // frame g-1 in [0,250); covers t in [gm1*256,(gm1+1)*256)
    const int b   = blockIdx.y;
    const int tid = threadIdx.x;

    __shared__ float sAprev[kC];  // A[b, g-1, :]
    __shared__ float sAcur[kC];   // A[b, min(g,249), :]
    __shared__ float sWin[kHop];

    // periodic hann 512, first half: w[r] = 0.5*(1 - cos(pi*r/256))
    sWin[tid] = 0.5f * (1.0f - cosf(kPi * (float)tid * (1.0f / 256.0f)));

    if (tid < 2 * kC) {
        const int which = (tid >= kC) ? 1 : 0;   // 0 -> frame g-1, 1 -> frame min(g,249)
        const int c = which ? (tid - kC) : tid;
        const int frame = which ? min(gm1 + 1, kF - 1) : gm1;
        const int idx = (b * kF + frame) * kC + c;
        const float xa = amp_in[idx];
        const float xf = frq_in[idx];
        const float a  = 2.0f * powf(sigmoidf_(xa), kLog10) + 1e-7f;
        const float f  = 440.0f * exp2f((sigmoidf_(xf) * kMidiMax - 69.0f) * (1.0f / 12.0f));
        const float aa = (f * (float)(c + 1) < 22050.0f) ? (1.0f + 1e-4f) : 1e-4f;
        const float A = a * aa;
        if (which) sAcur[c] = A; else sAprev[c] = A;
    }
    __syncthreads();

    // 256 samples * 100 ch = 25600 coalesced scalar f32 stores per block:
    // element k: sample q = k/100, channel c = k%100.
    const size_t base = ((size_t)b * kSamples + (size_t)gm1 * kHop) * (size_t)kC;
    for (int k = tid; k < kHop * kC; k += 256) {
        const int q = k / 100;
        const int c = k - q * 100;
        const float wr = sWin[q];
        const float ap = sAprev[c];
        const float ag = sAcur[c];
        amp_out[base + (size_t)k] = fmaf(wr, ag - ap, ap);
    }
}

__global__ __launch_bounds__(256) void freq_kernel(
    const float* frq_in,
    float* frq_out)
{
    const int i = blockIdx.x * 256 + threadIdx.x;
    if (i < kFreqElems) {
        const float xf = frq_in[i];
        frq_out[i] = 440.0f * exp2f((sigmoidf_(xf) * kMidiMax - 69.0f) * (1.0f / 12.0f));
    }
}

extern "C" void kernel_launch(void* const* d_in, const int* in_sizes, int n_in,
                              void* d_out, int out_size, void* d_ws, size_t ws_size,
                              hipStream_t stream) {
    (void)in_sizes; (void)n_in; (void)out_size; (void)d_ws; (void)ws_size;
    const float* amp = (const float*)d_in[0];
    const float* frq = (const float*)d_in[1];
    float* out0 = (float*)d_out;           // amp env, f32 elems [0, 51.2M)
    float* out1 = out0 + kAmpElems;        // freq env, f32 elems [51.2M, 51.4M)

    dim3 grid(kF, kB);
    amp_kernel<<<grid, 256, 0, stream>>>(amp, frq, out0);

    const int fblocks = (kFreqElems + 255) / 256;   // 782
    freq_kernel<<<fblocks, 256, 0, stream>>>(frq, out1);
}